// Round 14
// baseline (101.450 us; speedup 1.0000x reference)
//
#include <hip/hip_runtime.h>

#define B_ 8
#define L_ 1024
#define H_ 8
#define DM_ 640

typedef __attribute__((ext_vector_type(8))) short bf16x8;
typedef __attribute__((ext_vector_type(4))) short bf16x4;
typedef __attribute__((ext_vector_type(4))) float f32x4;
typedef __attribute__((ext_vector_type(2))) float f32x2;
typedef __attribute__((ext_vector_type(2))) int i32x2;
typedef __attribute__((ext_vector_type(4))) unsigned short us4;
typedef __attribute__((ext_vector_type(8))) unsigned short us8;

#if __has_builtin(__builtin_amdgcn_exp2f)
#define EXP2F __builtin_amdgcn_exp2f
#else
#define EXP2F exp2f
#endif

#define C1F 0.22195308f  // 2*log2(e)/13
#define C2F 0.11097654f  // log2(e)/13

// d_out layout: [0, 10616832)            Vtp bf16 V' tiles [64bh][16kt][81 rows][64 keys]
//                                        rows 0..79 = w'*V transposed, row 80 = w'
//               [10616832, 15859712)     attn fp8 e4m3 [8192][640]
// ws layout:    [0, 6291456)             Kp8 fp8(K*C1) [64bh][1024][96B] (bytes 80..95 = 0)
//               (fc overwrites ws with x bf16; ln overwrites d_out with y)
#define VTP_TILE_SHORTS 5184     // 81*64
#define ATTN8_OFF 10616832       // bytes into d_out
#define KP_ROW_B 96              // bytes per key row (80 data + 16 zero pad)

__device__ __forceinline__ unsigned short f2bf(float f) {
  unsigned int u = __builtin_bit_cast(unsigned int, f);
  u += 0x7fffu + ((u >> 16) & 1u);
  return (unsigned short)(u >> 16);
}
__device__ __forceinline__ float bf2f(unsigned short h) {
  unsigned int u = ((unsigned int)h) << 16;
  return __builtin_bit_cast(float, u);
}
__device__ __forceinline__ float sane(float x, float lim) {
  return fminf(fmaxf(x, -lim), lim);  // also maps NaN -> -lim
}
__device__ __forceinline__ unsigned cvt_pk_bf16(float a, float b) {
  unsigned r;
  asm("v_cvt_pk_bf16_f32 %0, %1, %2" : "=v"(r) : "v"(a), "v"(b));
  return r;
}

// -------------------- Kernel 0: prep --------------------
// Kp8 = fp8(k*C1) rows of 96B (tail zeroed); Vtp rows 0..79 = bf16(w'*v) transposed,
// row 80 = bf16(w'), w' = exp2((80-||k||^2)*C2) (constant cancels in num/denom).
__global__ __launch_bounds__(256) void prep_kernel(
    const float* __restrict__ kg, const float* __restrict__ vg,
    unsigned char* __restrict__ Kp8, unsigned short* __restrict__ Vtp) {
  __shared__ float V_lds[64 * 81];
  __shared__ float w_lds[64];
  const int tid = threadIdx.x;
  const int bh = blockIdx.x >> 4, kt = blockIdx.x & 15;
  const int b = bh >> 3, h = bh & 7;
  const int key = tid >> 2, part = tid & 3;
  const int keyg = kt * 64 + key;

  const float* krow = kg + (size_t)(b * L_ + keyg) * DM_ + h * 80 + part * 20;
  const float* vrow = vg + (size_t)(b * L_ + keyg) * DM_ + h * 80 + part * 20;
  unsigned char* kpr = Kp8 + ((size_t)bh * L_ + keyg) * KP_ROW_B + part * 20;

  float ssq = 0.f;
#pragma unroll
  for (int i = 0; i < 5; ++i) {
    float4 f = *(const float4*)(krow + 4 * i);
    ssq += f.x * f.x + f.y * f.y + f.z * f.z + f.w * f.w;
    int pk = __builtin_amdgcn_cvt_pk_fp8_f32(f.x * C1F, f.y * C1F, 0, false);
    pk = __builtin_amdgcn_cvt_pk_fp8_f32(f.z * C1F, f.w * C1F, pk, true);
    *(unsigned*)(kpr + 4 * i) = (unsigned)pk;
    float4 g4 = *(const float4*)(vrow + 4 * i);
    int d0 = part * 20 + 4 * i;
    V_lds[key * 81 + d0 + 0] = g4.x;
    V_lds[key * 81 + d0 + 1] = g4.y;
    V_lds[key * 81 + d0 + 2] = g4.z;
    V_lds[key * 81 + d0 + 3] = g4.w;
  }
  if (part == 0) {  // zero pad bytes 80..95 (row base is 16B-aligned: 96 = 6*16)
    uint4 z = {0, 0, 0, 0};
    *(uint4*)(Kp8 + ((size_t)bh * L_ + keyg) * KP_ROW_B + 80) = z;
  }
  ssq += __shfl_xor(ssq, 1);
  ssq += __shfl_xor(ssq, 2);
  if (part == 0) w_lds[key] = EXP2F((80.f - ssq) * C2F);
  __syncthreads();

  unsigned short* vt = Vtp + (size_t)(bh * 16 + kt) * VTP_TILE_SHORTS;
#pragma unroll
  for (int r = 0; r < 11; ++r) {
    int p = r * 256 + tid;
    if (p < 81 * 32) {
      int dv = p >> 5, kp = (p & 31) * 2;
      float wa = w_lds[kp], wb = w_lds[kp + 1];
      float va = (dv < 80) ? V_lds[kp * 81 + dv] * wa : wa;
      float vb = (dv < 80) ? V_lds[(kp + 1) * 81 + dv] * wb : wb;
      *(unsigned*)(vt + dv * 64 + kp) =
          (unsigned)f2bf(va) | ((unsigned)f2bf(vb) << 16);
    }
  }
}

// -------------------- Kernel A: flash attention (2x2 wave split, 4 blocks/CU) ----------
// 4-wave blocks, QBLK=64, grid 1024, __launch_bounds__(256,4): LDS 38.9KB x 4 = 155.6KB
// -> 4 resident blocks/CU (4 independent barrier domains). Wave (kw=wid>>1, qw=wid&1)
// handles key-tiles {2kw,2kw+1} x q-subtiles {2qw,2qw+1}: each K/V LDS fragment feeds
// 2 MFMAs (18 b64 reads/wave-kt vs 36). O/l partials combined once via LDS scratch.
// Dbuf, 1 barrier/kt; p = exp2(C1*q.k) (bounded); PV via 16x16x16 bf16 MFMA;
// l = sum_k w'_k p_k in VALU.
#define KSTRB 112  // bytes per K row in LDS
#define VSTR 76    // shorts (odd-pair spread -> conflict-free b64 PV reads)

__global__ __launch_bounds__(256, 4) void attn_kernel(
    const float* __restrict__ qg, const unsigned char* __restrict__ Kp8,
    const unsigned short* __restrict__ Vtp, unsigned char* __restrict__ attn8) {
  __shared__ __align__(16) unsigned char K_lds[2][64 * KSTRB];
  __shared__ __align__(16) unsigned short Vt_lds[2][80 * VSTR];
  __shared__ __align__(16) unsigned short w_sh[2][64];

  const int tid = threadIdx.x;
  const int wid = tid >> 6, lane = tid & 63;
  const int col = lane & 15, g = lane >> 4;
  const int kw = wid >> 1, qw = wid & 1;
  const int bx = blockIdx.x;
  const int bh = bx & 63, qt = bx >> 6;  // same-bh blocks 64 apart -> same XCD slot
  const int b = bh >> 3, h = bh & 7;

  // staging coords: K = 384 uint4 chunks (64 rows x 6), V = 640 us8 (80 rows x 8), w' = 8
  const int kf0 = tid, kf1 = tid + 256;               // kf1 if tid < 128
  const int kr0 = kf0 / 6, kc0 = kf0 - kr0 * 6;
  const int kr1 = kf1 / 6, kc1 = kf1 - kr1 * 6;
  const int va0 = tid, va1 = tid + 256, va2 = tid + 512;  // va2 if tid < 128
  const int vr0 = va0 >> 3, vc0 = va0 & 7;
  const int vr1 = va1 >> 3, vc1 = va1 & 7;
  const int vr2 = va2 >> 3, vc2 = va2 & 7;

  const unsigned char* kslice = Kp8 + (size_t)bh * L_ * KP_ROW_B;
  const unsigned short* vslice = Vtp + (size_t)(bh * 16) * VTP_TILE_SHORTS;

  uint4 sk0, sk1;
  us8 sv0, sv1, sv2, sw;
  auto load_tile = [&](int kt) {
    const unsigned char* kb = kslice + (size_t)kt * 64 * KP_ROW_B;
    const unsigned short* vb = vslice + (size_t)kt * VTP_TILE_SHORTS;
    sk0 = *(const uint4*)(kb + kr0 * KP_ROW_B + kc0 * 16);
    if (tid < 128) sk1 = *(const uint4*)(kb + kr1 * KP_ROW_B + kc1 * 16);
    sv0 = *(const us8*)(vb + vr0 * 64 + vc0 * 8);
    sv1 = *(const us8*)(vb + vr1 * 64 + vc1 * 8);
    if (tid < 128) sv2 = *(const us8*)(vb + vr2 * 64 + vc2 * 8);
    if (tid < 8) sw = *(const us8*)(vb + 5120 + tid * 8);
  };
  auto write_tile = [&](int bf) {
    *(uint4*)&K_lds[bf][kr0 * KSTRB + kc0 * 16] = sk0;
    if (tid < 128) *(uint4*)&K_lds[bf][kr1 * KSTRB + kc1 * 16] = sk1;
    *(us8*)&Vt_lds[bf][vr0 * VSTR + vc0 * 8] = sv0;
    *(us8*)&Vt_lds[bf][vr1 * VSTR + vc1 * 8] = sv1;
    if (tid < 128) *(us8*)&Vt_lds[bf][vr2 * VSTR + vc2 * 8] = sv2;
    if (tid < 8) *(us8*)&w_sh[bf][tid * 8] = sw;
  };

  // Q fragments fp8 for the wave's two q-subtiles (2qw, 2qw+1)
  long qa[2][3];
  {
#pragma unroll
    for (int j = 0; j < 2; ++j) {
      const int qrow = qt * 64 + (qw * 2 + j) * 16 + col;
      const float* qr = qg + (size_t)(b * L_ + qrow) * DM_ + h * 80;
#pragma unroll
      for (int c = 0; c < 3; ++c) {
        int d0 = c * 32 + g * 8;
        if (d0 < 80) {
          float4 f0 = *(const float4*)(qr + d0);
          float4 f1 = *(const float4*)(qr + d0 + 4);
          int lo = __builtin_amdgcn_cvt_pk_fp8_f32(f0.x, f0.y, 0, false);
          lo = __builtin_amdgcn_cvt_pk_fp8_f32(f0.z, f0.w, lo, true);
          int hi = __builtin_amdgcn_cvt_pk_fp8_f32(f1.x, f1.y, 0, false);
          hi = __builtin_amdgcn_cvt_pk_fp8_f32(f1.z, f1.w, hi, true);
          i32x2 q2 = {lo, hi};
          qa[j][c] = __builtin_bit_cast(long, q2);
        } else {
          qa[j][c] = 0;
        }
      }
    }
  }

  f32x4 acc_o[2][5];  // [q-subtile j][u]  (partial: this wave's 32 keys only)
#pragma unroll
  for (int j = 0; j < 2; ++j)
#pragma unroll
    for (int u = 0; u < 5; ++u) {
      f32x4 z = {0.f, 0.f, 0.f, 0.f};
      acc_o[j][u] = z;
    }
  float lp[2] = {0.f, 0.f};

  load_tile(0);
  write_tile(0);
  __syncthreads();

  for (int kt = 0; kt < 16; ++kt) {
    const int cur = kt & 1;
    if (kt < 15) load_tile(kt + 1);  // global loads in flight during compute

    // QK^T (fp8): for the wave's 2 key-tiles x 2 q-subtiles
    f32x4 accS[2][2];  // [j][i]
#pragma unroll
    for (int j = 0; j < 2; ++j)
#pragma unroll
      for (int i = 0; i < 2; ++i) {
        f32x4 z = {0.f, 0.f, 0.f, 0.f};
        accS[j][i] = z;
      }
#pragma unroll
    for (int i = 0; i < 2; ++i) {
      const int t = kw * 2 + i;
      const unsigned char* tb = &K_lds[cur][(t * 16 + col) * KSTRB];
      long k0 = *(const long*)(tb + g * 8);
      long k1 = *(const long*)(tb + 32 + g * 8);
      long k2 = *(const long*)(tb + 64 + g * 8);
#pragma unroll
      for (int j = 0; j < 2; ++j) {
        accS[j][i] = __builtin_amdgcn_mfma_f32_16x16x32_fp8_fp8(k0, qa[j][0], accS[j][i], 0, 0, 0);
        accS[j][i] = __builtin_amdgcn_mfma_f32_16x16x32_fp8_fp8(k1, qa[j][1], accS[j][i], 0, 0, 0);
        accS[j][i] = __builtin_amdgcn_mfma_f32_16x16x32_fp8_fp8(k2, qa[j][2], accS[j][i], 0, 0, 0);
      }
    }

    // softmax numerators, l-dot, pack, PV (V frag shared across the 2 q-subtiles)
#pragma unroll
    for (int i = 0; i < 2; ++i) {
      const int t = kw * 2 + i;
      us4 w4 = *(const us4*)&w_sh[cur][t * 16 + g * 4];
      float w0 = bf2f(w4[0]), w1 = bf2f(w4[1]), w2 = bf2f(w4[2]), w3 = bf2f(w4[3]);
      bf16x4 pf[2];
#pragma unroll
      for (int j = 0; j < 2; ++j) {
        float p0 = EXP2F(accS[j][i][0]), p1 = EXP2F(accS[j][i][1]);
        float p2 = EXP2F(accS[j][i][2]), p3 = EXP2F(accS[j][i][3]);
        lp[j] += p0 * w0 + p1 * w1 + p2 * w2 + p3 * w3;
        i32x2 pw = {(int)cvt_pk_bf16(p0, p1), (int)cvt_pk_bf16(p2, p3)};
        pf[j] = __builtin_bit_cast(bf16x4, pw);
      }
#pragma unroll
      for (int u = 0; u < 5; ++u) {
        bf16x4 vf = *(const bf16x4*)&Vt_lds[cur][(u * 16 + col) * VSTR + t * 16 + g * 4];
        acc_o[0][u] = __builtin_amdgcn_mfma_f32_16x16x16bf16_1k(vf, pf[0], acc_o[0][u], 0, 0, 0);
        acc_o[1][u] = __builtin_amdgcn_mfma_f32_16x16x16bf16_1k(vf, pf[1], acc_o[1][u], 0, 0, 0);
      }
    }

    if (kt < 15) {
      write_tile(cur ^ 1);  // buf cur^1's readers finished before the last barrier
      __syncthreads();
    }
  }

  // ---- cross-kw reduction via LDS scratch (reuses Vt_lds; 2x11264B <= 24320B) ----
  float* scr = (float*)&Vt_lds[0][0];  // layout: [qw][lane][44 floats]
  float* my = scr + (qw * 64 + lane) * 44;
  __syncthreads();  // all PV reads of Vt_lds done
  if (kw == 1) {
#pragma unroll
    for (int j = 0; j < 2; ++j)
#pragma unroll
      for (int u = 0; u < 5; ++u)
        *(f32x4*)(my + (j * 5 + u) * 4) = acc_o[j][u];
    f32x4 lv = {lp[0], lp[1], 0.f, 0.f};
    *(f32x4*)(my + 40) = lv;
  }
  __syncthreads();
  if (kw == 0) {
#pragma unroll
    for (int j = 0; j < 2; ++j)
#pragma unroll
      for (int u = 0; u < 5; ++u) {
        f32x4 pv = *(const f32x4*)(my + (j * 5 + u) * 4);
        acc_o[j][u] += pv;
      }
    f32x4 lv = *(const f32x4*)(my + 40);
    lp[0] += lv[0];
    lp[1] += lv[1];

#pragma unroll
    for (int j = 0; j < 2; ++j) {
      float l = lp[j] + __shfl_xor(lp[j], 16);
      l += __shfl_xor(l, 32);
      float invl = 1.0f / fmaxf(l, 1e-30f);
      const int qrow = qt * 64 + (qw * 2 + j) * 16 + col;
      unsigned char* ob = attn8 + (size_t)(b * L_ + qrow) * DM_ + h * 80;
#pragma unroll
      for (int u = 0; u < 5; ++u) {
        float o0 = sane(acc_o[j][u][0] * invl, 240.f);
        float o1 = sane(acc_o[j][u][1] * invl, 240.f);
        float o2 = sane(acc_o[j][u][2] * invl, 240.f);
        float o3 = sane(acc_o[j][u][3] * invl, 240.f);
        int pk = __builtin_amdgcn_cvt_pk_fp8_f32(o0, o1, 0, false);
        pk = __builtin_amdgcn_cvt_pk_fp8_f32(o2, o3, pk, true);
        *(int*)(ob + u * 16 + g * 4) = pk;
      }
    }
  }
}

// -------------------- Kernel B: fc GEMM, 64x64 tiles, grid 1280 (~5 blocks/CU) --------
// bf16 MFMA; A upconverted from fp8 in staging; dbuf, 1 barrier/k-chunk.
#define BSTR 40  // shorts
__global__ __launch_bounds__(256) void fc_kernel(
    const unsigned char* __restrict__ attn8, const float* __restrict__ w,
    const float* __restrict__ fcb, const float* __restrict__ gamma,
    const float* __restrict__ qres, unsigned short* __restrict__ xout) {
  __shared__ __align__(16) unsigned short A_lds[2][64 * BSTR];
  __shared__ __align__(16) unsigned short B_lds[2][64 * BSTR];

  const int tid = threadIdx.x;
  const int wid = tid >> 6, lane = tid & 63;
  const int col = lane & 15, g = lane >> 4;
  const int rt = blockIdx.x / 10, cn = blockIdx.x % 10;
  const int wm = wid >> 1, wn = wid & 1;
  const int r = tid >> 2, sg = tid & 3;

  f32x4 acc[2][2];
#pragma unroll
  for (int m = 0; m < 2; ++m)
#pragma unroll
    for (int n = 0; n < 2; ++n) {
      f32x4 z = {0.f, 0.f, 0.f, 0.f};
      acc[m][n] = z;
    }

  uint2 sa;
  float4 sb0, sb1;
  auto load_k = [&](int kc) {
    sa = *(const uint2*)(attn8 + (size_t)(rt * 64 + r) * DM_ + kc * 32 + sg * 8);
    const float* wsrc = w + (size_t)(cn * 64 + r) * DM_ + kc * 32 + sg * 8;
    sb0 = *(const float4*)wsrc;
    sb1 = *(const float4*)(wsrc + 4);
  };
  auto write_k = [&](int bf) {
    const unsigned* adw = (const unsigned*)&sa;
    unsigned ow[4];
#pragma unroll
    for (int d = 0; d < 2; ++d) {
      f32x2 lo = __builtin_amdgcn_cvt_pk_f32_fp8(adw[d], false);
      f32x2 hi = __builtin_amdgcn_cvt_pk_f32_fp8(adw[d], true);
      ow[2 * d] = cvt_pk_bf16(lo[0], lo[1]);
      ow[2 * d + 1] = cvt_pk_bf16(hi[0], hi[1]);
    }
    *(uint4*)&A_lds[bf][r * BSTR + sg * 8] = *(const uint4*)ow;
    unsigned bw[4] = {cvt_pk_bf16(sb0.x, sb0.y), cvt_pk_bf16(sb0.z, sb0.w),
                      cvt_pk_bf16(sb1.x, sb1.y), cvt_pk_bf16(sb1.z, sb1.w)};
    *(uint4*)&B_lds[bf][r * BSTR + sg * 8] = *(const uint4*)bw;
  };

  load_k(0);
  write_k(0);
  __syncthreads();

  for (int kc = 0; kc < 20; ++kc) {
    const int cur = kc & 1;
    if (kc < 19) load_k(kc + 1);

    bf16x8 af[2], bfr[2];
#pragma unroll
    for (int m = 0; m < 2; ++m)
      af[m] = *(const bf16x8*)&A_lds[cur][(wm * 32 + m * 16 + col) * BSTR + g * 8];
#pragma unroll
    for (int n = 0; n < 2; ++n)
      bfr[n] = *(const bf16x8*)&B_lds[cur][(wn * 32 + n * 16 + col) * BSTR + g * 8];
#pragma unroll
    for (int m = 0; m < 2; ++m)
#pragma unroll
      for (int n = 0; n < 2; ++n)
        acc[m][n] = __builtin_amdgcn_mfma_f32_16x16x32_bf16(af[m], bfr[n], acc[m][n], 0, 0, 0);

    if (kc < 19) {
      write_k(cur ^ 1);
      __syncthreads();
    }
  }

  int jcol[2];
  float fb2[2], gm[2];
#pragma unroll
  for (int n = 0; n < 2; ++n) {
    jcol[n] = cn * 64 + wn * 32 + n * 16 + col;
    fb2[n] = fcb[jcol[n]];
    gm[n] = gamma[jcol[n]];
  }
#pragma unroll
  for (int m = 0; m < 2; ++m) {
    int rowg = rt * 64 + wm * 32 + m * 16 + g * 4;
#pragma unroll
    for (int j = 0; j < 4; ++j) {
      int row = rowg + j;
#pragma unroll
      for (int n = 0; n < 2; ++n) {
        float xv = (acc[m][n][j] + fb2[n]) * gm[n] + qres[(size_t)row * DM_ + jcol[n]];
        xout[(size_t)row * DM_ + jcol[n]] = f2bf(sane(xv, 1e5f));
      }
    }
  }
}

// -------------------- Kernel C: LayerNorm (x bf16 -> y fp32) --------------------
__global__ __launch_bounds__(256) void ln_kernel(
    const unsigned short* __restrict__ x, const float* __restrict__ lw,
    const float* __restrict__ lb, float* __restrict__ y) {
  const int wid = threadIdx.x >> 6, lane = threadIdx.x & 63;
  const int row = blockIdx.x * 4 + wid;
  const unsigned short* xr = x + (size_t)row * DM_;

  unsigned int u[5];
  float s = 0.f, ss = 0.f;
#pragma unroll
  for (int i = 0; i < 5; ++i) {
    u[i] = *(const unsigned int*)(xr + 2 * (lane + 64 * i));
    float a0 = bf2f((unsigned short)(u[i] & 0xffff));
    float a1 = bf2f((unsigned short)(u[i] >> 16));
    s += a0 + a1;
    ss += a0 * a0 + a1 * a1;
  }
#pragma unroll
  for (int d = 1; d < 64; d <<= 1) {
    s += __shfl_xor(s, d);
    ss += __shfl_xor(ss, d);
  }
  const float mu = s * (1.f / 640.f);
  const float var = ss * (1.f / 640.f) - mu * mu;
  const float rstd = rsqrtf(var + 1e-5f);

  float* yr = y + (size_t)row * DM_;
#pragma unroll
  for (int i = 0; i < 5; ++i) {
    int c0 = 2 * (lane + 64 * i);
    float a0 = bf2f((unsigned short)(u[i] & 0xffff));
    float a1 = bf2f((unsigned short)(u[i] >> 16));
    float2 wv = *(const float2*)(lw + c0);
    float2 bv = *(const float2*)(lb + c0);
    float2 out;
    out.x = (a0 - mu) * rstd * wv.x + bv.x;
    out.y = (a1 - mu) * rstd * wv.y + bv.y;
    *(float2*)(yr + c0) = out;
  }
}

extern "C" void kernel_launch(void* const* d_in, const int* in_sizes, int n_in,
                              void* d_out, int out_size, void* d_ws, size_t ws_size,
                              hipStream_t stream) {
  const float* q = (const float*)d_in[0];
  const float* k = (const float*)d_in[1];
  const float* v = (const float*)d_in[2];
  const float* fw = (const float*)d_in[3];
  const float* fb = (const float*)d_in[4];
  const float* g1 = (const float*)d_in[5];
  const float* lw = (const float*)d_in[6];
  const float* lb = (const float*)d_in[7];

  unsigned short* vtp = (unsigned short*)d_out;                   // 10.62 MB V' tiles
  unsigned char* attn8 = (unsigned char*)d_out + ATTN8_OFF;       // 5.24 MB fp8 attn
  unsigned char* kp8 = (unsigned char*)d_ws;                      // 6.29 MB fp8 Kp
  unsigned short* xws = (unsigned short*)d_ws;                    // x overwrites Kp
  float* y = (float*)d_out;                                        // final overwrite

  prep_kernel<<<dim3(64 * 16), dim3(256), 0, stream>>>(k, v, kp8, vtp);
  attn_kernel<<<dim3(64 * 16), dim3(256), 0, stream>>>(q, kp8, vtp, attn8);
  fc_kernel<<<dim3(128 * 10), dim3(256), 0, stream>>>(attn8, fw, fb, g1, q, xws);
  ln_kernel<<<dim3(8192 / 4), dim3(256), 0, stream>>>(xws, lw, lb, y);
}

// Round 15
// 84.127 us; speedup vs baseline: 1.2059x; 1.2059x over previous
//
#include <hip/hip_runtime.h>

#define B_ 8
#define L_ 1024
#define H_ 8
#define DM_ 640

typedef __attribute__((ext_vector_type(8))) short bf16x8;
typedef __attribute__((ext_vector_type(4))) short bf16x4;
typedef __attribute__((ext_vector_type(4))) float f32x4;
typedef __attribute__((ext_vector_type(2))) float f32x2;
typedef __attribute__((ext_vector_type(2))) int i32x2;
typedef __attribute__((ext_vector_type(4))) unsigned short us4;
typedef __attribute__((ext_vector_type(8))) unsigned short us8;

#if __has_builtin(__builtin_amdgcn_exp2f)
#define EXP2F __builtin_amdgcn_exp2f
#else
#define EXP2F exp2f
#endif

#define C1F 0.22195308f  // 2*log2(e)/13
#define C2F 0.11097654f  // log2(e)/13

// d_out layout: [0, 10616832)            Vtp bf16 V' tiles [64bh][16kt][81 rows][64 keys]
//                                        rows 0..79 = w'*V transposed, row 80 = w'
//               [10616832, 15859712)     attn fp8 e4m3 [8192][640]
// ws layout:    [0, 6291456)             Kp8 fp8(K*C1) [64bh][1024][96B] (bytes 80..95 = 0)
//               (fc overwrites ws with x bf16; ln overwrites d_out with y)
#define VTP_TILE_SHORTS 5184     // 81*64
#define ATTN8_OFF 10616832       // bytes into d_out
#define KP_ROW_B 96              // bytes per key row (80 data + 16 zero pad)

__device__ __forceinline__ unsigned short f2bf(float f) {
  unsigned int u = __builtin_bit_cast(unsigned int, f);
  u += 0x7fffu + ((u >> 16) & 1u);
  return (unsigned short)(u >> 16);
}
__device__ __forceinline__ float bf2f(unsigned short h) {
  unsigned int u = ((unsigned int)h) << 16;
  return __builtin_bit_cast(float, u);
}
__device__ __forceinline__ float sane(float x, float lim) {
  return fminf(fmaxf(x, -lim), lim);  // also maps NaN -> -lim
}
__device__ __forceinline__ unsigned cvt_pk_bf16(float a, float b) {
  unsigned r;
  asm("v_cvt_pk_bf16_f32 %0, %1, %2" : "=v"(r) : "v"(a), "v"(b));
  return r;
}

// -------------------- Kernel 0: prep --------------------
// Kp8 = fp8(k*C1) rows of 96B (tail zeroed); Vtp rows 0..79 = bf16(w'*v) transposed,
// row 80 = bf16(w'), w' = exp2((80-||k||^2)*C2) (constant cancels in num/denom).
__global__ __launch_bounds__(256) void prep_kernel(
    const float* __restrict__ kg, const float* __restrict__ vg,
    unsigned char* __restrict__ Kp8, unsigned short* __restrict__ Vtp) {
  __shared__ float V_lds[64 * 81];
  __shared__ float w_lds[64];
  const int tid = threadIdx.x;
  const int bh = blockIdx.x >> 4, kt = blockIdx.x & 15;
  const int b = bh >> 3, h = bh & 7;
  const int key = tid >> 2, part = tid & 3;
  const int keyg = kt * 64 + key;

  const float* krow = kg + (size_t)(b * L_ + keyg) * DM_ + h * 80 + part * 20;
  const float* vrow = vg + (size_t)(b * L_ + keyg) * DM_ + h * 80 + part * 20;
  unsigned char* kpr = Kp8 + ((size_t)bh * L_ + keyg) * KP_ROW_B + part * 20;

  float ssq = 0.f;
#pragma unroll
  for (int i = 0; i < 5; ++i) {
    float4 f = *(const float4*)(krow + 4 * i);
    ssq += f.x * f.x + f.y * f.y + f.z * f.z + f.w * f.w;
    int pk = __builtin_amdgcn_cvt_pk_fp8_f32(f.x * C1F, f.y * C1F, 0, false);
    pk = __builtin_amdgcn_cvt_pk_fp8_f32(f.z * C1F, f.w * C1F, pk, true);
    *(unsigned*)(kpr + 4 * i) = (unsigned)pk;
    float4 g4 = *(const float4*)(vrow + 4 * i);
    int d0 = part * 20 + 4 * i;
    V_lds[key * 81 + d0 + 0] = g4.x;
    V_lds[key * 81 + d0 + 1] = g4.y;
    V_lds[key * 81 + d0 + 2] = g4.z;
    V_lds[key * 81 + d0 + 3] = g4.w;
  }
  if (part == 0) {  // zero pad bytes 80..95 (row base is 16B-aligned: 96 = 6*16)
    uint4 z = {0, 0, 0, 0};
    *(uint4*)(Kp8 + ((size_t)bh * L_ + keyg) * KP_ROW_B + 80) = z;
  }
  ssq += __shfl_xor(ssq, 1);
  ssq += __shfl_xor(ssq, 2);
  if (part == 0) w_lds[key] = EXP2F((80.f - ssq) * C2F);
  __syncthreads();

  unsigned short* vt = Vtp + (size_t)(bh * 16 + kt) * VTP_TILE_SHORTS;
#pragma unroll
  for (int r = 0; r < 11; ++r) {
    int p = r * 256 + tid;
    if (p < 81 * 32) {
      int dv = p >> 5, kp = (p & 31) * 2;
      float wa = w_lds[kp], wb = w_lds[kp + 1];
      float va = (dv < 80) ? V_lds[kp * 81 + dv] * wa : wa;
      float vb = (dv < 80) ? V_lds[(kp + 1) * 81 + dv] * wb : wb;
      *(unsigned*)(vt + dv * 64 + kp) =
          (unsigned)f2bf(va) | ((unsigned)f2bf(vb) << 16);
    }
  }
}

// -------------------- Kernel A: flash attention (phase-split kt body) --------------------
// 4-wave blocks, QBLK=64, grid 1024 -> 4 blocks/CU (LDS 39KB). Dbuf, 1 barrier/kt.
// kt body in 3 phases: P1 all 12 QK ds_reads -> 12 fp8 MFMAs; P2 w' + exp2 + l-dot +
// pack (VALU only); P3 PV in 2 half-phases of 10 ds_reads -> 10 bf16 16x16x16 MFMAs.
#define KSTRB 112  // bytes per K row in LDS
#define VSTR 76    // shorts (odd-pair spread -> conflict-free b64 PV reads)

__global__ __launch_bounds__(256, 4) void attn_kernel(
    const float* __restrict__ qg, const unsigned char* __restrict__ Kp8,
    const unsigned short* __restrict__ Vtp, unsigned char* __restrict__ attn8) {
  __shared__ __align__(16) unsigned char K_lds[2][64 * KSTRB];
  __shared__ __align__(16) unsigned short Vt_lds[2][80 * VSTR];
  __shared__ __align__(16) unsigned short w_sh[2][64];

  const int tid = threadIdx.x;
  const int wid = tid >> 6, lane = tid & 63;
  const int col = lane & 15, g = lane >> 4;
  const int bx = blockIdx.x;
  const int bh = bx & 63, qt = bx >> 6;  // same-bh blocks 64 apart -> same XCD slot
  const int b = bh >> 3, h = bh & 7;

  // staging coords: K = 384 uint4 chunks (64 rows x 6), V = 640 us8 (80 rows x 8), w' = 8
  const int kf0 = tid, kf1 = tid + 256;               // kf1 if tid < 128
  const int kr0 = kf0 / 6, kc0 = kf0 - kr0 * 6;
  const int kr1 = kf1 / 6, kc1 = kf1 - kr1 * 6;
  const int va0 = tid, va1 = tid + 256, va2 = tid + 512;  // va2 if tid < 128
  const int vr0 = va0 >> 3, vc0 = va0 & 7;
  const int vr1 = va1 >> 3, vc1 = va1 & 7;
  const int vr2 = va2 >> 3, vc2 = va2 & 7;

  const unsigned char* kslice = Kp8 + (size_t)bh * L_ * KP_ROW_B;
  const unsigned short* vslice = Vtp + (size_t)(bh * 16) * VTP_TILE_SHORTS;

  uint4 sk0, sk1;
  us8 sv0, sv1, sv2, sw;
  auto load_tile = [&](int kt) {
    const unsigned char* kb = kslice + (size_t)kt * 64 * KP_ROW_B;
    const unsigned short* vb = vslice + (size_t)kt * VTP_TILE_SHORTS;
    sk0 = *(const uint4*)(kb + kr0 * KP_ROW_B + kc0 * 16);
    if (tid < 128) sk1 = *(const uint4*)(kb + kr1 * KP_ROW_B + kc1 * 16);
    sv0 = *(const us8*)(vb + vr0 * 64 + vc0 * 8);
    sv1 = *(const us8*)(vb + vr1 * 64 + vc1 * 8);
    if (tid < 128) sv2 = *(const us8*)(vb + vr2 * 64 + vc2 * 8);
    if (tid < 8) sw = *(const us8*)(vb + 5120 + tid * 8);
  };
  auto write_tile = [&](int bf) {
    *(uint4*)&K_lds[bf][kr0 * KSTRB + kc0 * 16] = sk0;
    if (tid < 128) *(uint4*)&K_lds[bf][kr1 * KSTRB + kc1 * 16] = sk1;
    *(us8*)&Vt_lds[bf][vr0 * VSTR + vc0 * 8] = sv0;
    *(us8*)&Vt_lds[bf][vr1 * VSTR + vc1 * 8] = sv1;
    if (tid < 128) *(us8*)&Vt_lds[bf][vr2 * VSTR + vc2 * 8] = sv2;
    if (tid < 8) *(us8*)&w_sh[bf][tid * 8] = sw;
  };

  // Q fragments fp8 (B-operand: lane col = q-row, dims c*32 + g*8 + e)
  long qa[3];
  {
    const int qrow = qt * 64 + wid * 16 + col;
    const float* qr = qg + (size_t)(b * L_ + qrow) * DM_ + h * 80;
#pragma unroll
    for (int c = 0; c < 3; ++c) {
      int d0 = c * 32 + g * 8;
      if (d0 < 80) {
        float4 f0 = *(const float4*)(qr + d0);
        float4 f1 = *(const float4*)(qr + d0 + 4);
        int lo = __builtin_amdgcn_cvt_pk_fp8_f32(f0.x, f0.y, 0, false);
        lo = __builtin_amdgcn_cvt_pk_fp8_f32(f0.z, f0.w, lo, true);
        int hi = __builtin_amdgcn_cvt_pk_fp8_f32(f1.x, f1.y, 0, false);
        hi = __builtin_amdgcn_cvt_pk_fp8_f32(f1.z, f1.w, hi, true);
        i32x2 q2 = {lo, hi};
        qa[c] = __builtin_bit_cast(long, q2);
      } else {
        qa[c] = 0;
      }
    }
  }

  f32x4 acc_o[5];
#pragma unroll
  for (int u = 0; u < 5; ++u) {
    f32x4 z = {0.f, 0.f, 0.f, 0.f};
    acc_o[u] = z;
  }
  float lp = 0.f;

  load_tile(0);
  write_tile(0);
  __syncthreads();

  for (int kt = 0; kt < 16; ++kt) {
    const int cur = kt & 1;
    if (kt < 15) load_tile(kt + 1);  // global loads in flight during compute

    // ---- phase 1: QK — issue ALL 12 ds_reads, then 12 MFMAs ----
    long kfr[4][3];
#pragma unroll
    for (int t = 0; t < 4; ++t) {
      const unsigned char* tb = &K_lds[cur][(t * 16 + col) * KSTRB];
      kfr[t][0] = *(const long*)(tb + g * 8);
      kfr[t][1] = *(const long*)(tb + 32 + g * 8);
      kfr[t][2] = *(const long*)(tb + 64 + g * 8);
    }
    f32x4 accS[4];
#pragma unroll
    for (int t = 0; t < 4; ++t) {
      f32x4 z = {0.f, 0.f, 0.f, 0.f};
      accS[t] = z;
    }
#pragma unroll
    for (int t = 0; t < 4; ++t) {
      accS[t] = __builtin_amdgcn_mfma_f32_16x16x32_fp8_fp8(kfr[t][0], qa[0], accS[t], 0, 0, 0);
      accS[t] = __builtin_amdgcn_mfma_f32_16x16x32_fp8_fp8(kfr[t][1], qa[1], accS[t], 0, 0, 0);
      accS[t] = __builtin_amdgcn_mfma_f32_16x16x32_fp8_fp8(kfr[t][2], qa[2], accS[t], 0, 0, 0);
    }

    // ---- phase 2: w' reads + softmax numerators + l-dot + pack ----
    us4 w4[4];
#pragma unroll
    for (int t = 0; t < 4; ++t) w4[t] = *(const us4*)&w_sh[cur][t * 16 + g * 4];
    bf16x4 pf[4];
#pragma unroll
    for (int t = 0; t < 4; ++t) {
      float p0 = EXP2F(accS[t][0]), p1 = EXP2F(accS[t][1]);
      float p2 = EXP2F(accS[t][2]), p3 = EXP2F(accS[t][3]);
      lp += p0 * bf2f(w4[t][0]) + p1 * bf2f(w4[t][1]) +
            p2 * bf2f(w4[t][2]) + p3 * bf2f(w4[t][3]);
      i32x2 pw = {(int)cvt_pk_bf16(p0, p1), (int)cvt_pk_bf16(p2, p3)};
      pf[t] = __builtin_bit_cast(bf16x4, pw);
    }

    // ---- phase 3: PV — two half-phases of 10 ds_reads then 10 MFMAs ----
#pragma unroll
    for (int th = 0; th < 2; ++th) {
      bf16x4 vf[2][5];
#pragma unroll
      for (int tt = 0; tt < 2; ++tt)
#pragma unroll
        for (int u = 0; u < 5; ++u)
          vf[tt][u] = *(const bf16x4*)&Vt_lds[cur][(u * 16 + col) * VSTR +
                                                   (th * 2 + tt) * 16 + g * 4];
#pragma unroll
      for (int tt = 0; tt < 2; ++tt)
#pragma unroll
        for (int u = 0; u < 5; ++u)
          acc_o[u] = __builtin_amdgcn_mfma_f32_16x16x16bf16_1k(
              vf[tt][u], pf[th * 2 + tt], acc_o[u], 0, 0, 0);
    }

    if (kt < 15) {
      write_tile(cur ^ 1);  // buf cur^1's readers finished before the last barrier
      __syncthreads();
    }
  }

  // l = cross-g reduce of lp (terms positive -> l > 0); fp8 output
  float l = lp + __shfl_xor(lp, 16);
  l += __shfl_xor(l, 32);
  float invl = 1.0f / fmaxf(l, 1e-30f);
  const int qrow = qt * 64 + wid * 16 + col;
  unsigned char* ob = attn8 + (size_t)(b * L_ + qrow) * DM_ + h * 80;
#pragma unroll
  for (int u = 0; u < 5; ++u) {
    float o0 = sane(acc_o[u][0] * invl, 240.f);
    float o1 = sane(acc_o[u][1] * invl, 240.f);
    float o2 = sane(acc_o[u][2] * invl, 240.f);
    float o3 = sane(acc_o[u][3] * invl, 240.f);
    int pk = __builtin_amdgcn_cvt_pk_fp8_f32(o0, o1, 0, false);
    pk = __builtin_amdgcn_cvt_pk_fp8_f32(o2, o3, pk, true);
    *(int*)(ob + u * 16 + g * 4) = pk;
  }
}

// -------------------- Kernel B: fc GEMM, 64x64 tiles, grid 1280 (~5 blocks/CU) --------
// bf16 MFMA; A upconverted from fp8 in staging; dbuf, 1 barrier/k-chunk.
#define BSTR 40  // shorts
__global__ __launch_bounds__(256) void fc_kernel(
    const unsigned char* __restrict__ attn8, const float* __restrict__ w,
    const float* __restrict__ fcb, const float* __restrict__ gamma,
    const float* __restrict__ qres, unsigned short* __restrict__ xout) {
  __shared__ __align__(16) unsigned short A_lds[2][64 * BSTR];
  __shared__ __align__(16) unsigned short B_lds[2][64 * BSTR];

  const int tid = threadIdx.x;
  const int wid = tid >> 6, lane = tid & 63;
  const int col = lane & 15, g = lane >> 4;
  const int rt = blockIdx.x / 10, cn = blockIdx.x % 10;
  const int wm = wid >> 1, wn = wid & 1;
  const int r = tid >> 2, sg = tid & 3;

  f32x4 acc[2][2];
#pragma unroll
  for (int m = 0; m < 2; ++m)
#pragma unroll
    for (int n = 0; n < 2; ++n) {
      f32x4 z = {0.f, 0.f, 0.f, 0.f};
      acc[m][n] = z;
    }

  uint2 sa;
  float4 sb0, sb1;
  auto load_k = [&](int kc) {
    sa = *(const uint2*)(attn8 + (size_t)(rt * 64 + r) * DM_ + kc * 32 + sg * 8);
    const float* wsrc = w + (size_t)(cn * 64 + r) * DM_ + kc * 32 + sg * 8;
    sb0 = *(const float4*)wsrc;
    sb1 = *(const float4*)(wsrc + 4);
  };
  auto write_k = [&](int bf) {
    const unsigned* adw = (const unsigned*)&sa;
    unsigned ow[4];
#pragma unroll
    for (int d = 0; d < 2; ++d) {
      f32x2 lo = __builtin_amdgcn_cvt_pk_f32_fp8(adw[d], false);
      f32x2 hi = __builtin_amdgcn_cvt_pk_f32_fp8(adw[d], true);
      ow[2 * d] = cvt_pk_bf16(lo[0], lo[1]);
      ow[2 * d + 1] = cvt_pk_bf16(hi[0], hi[1]);
    }
    *(uint4*)&A_lds[bf][r * BSTR + sg * 8] = *(const uint4*)ow;
    unsigned bw[4] = {cvt_pk_bf16(sb0.x, sb0.y), cvt_pk_bf16(sb0.z, sb0.w),
                      cvt_pk_bf16(sb1.x, sb1.y), cvt_pk_bf16(sb1.z, sb1.w)};
    *(uint4*)&B_lds[bf][r * BSTR + sg * 8] = *(const uint4*)bw;
  };

  load_k(0);
  write_k(0);
  __syncthreads();

  for (int kc = 0; kc < 20; ++kc) {
    const int cur = kc & 1;
    if (kc < 19) load_k(kc + 1);

    bf16x8 af[2], bfr[2];
#pragma unroll
    for (int m = 0; m < 2; ++m)
      af[m] = *(const bf16x8*)&A_lds[cur][(wm * 32 + m * 16 + col) * BSTR + g * 8];
#pragma unroll
    for (int n = 0; n < 2; ++n)
      bfr[n] = *(const bf16x8*)&B_lds[cur][(wn * 32 + n * 16 + col) * BSTR + g * 8];
#pragma unroll
    for (int m = 0; m < 2; ++m)
#pragma unroll
      for (int n = 0; n < 2; ++n)
        acc[m][n] = __builtin_amdgcn_mfma_f32_16x16x32_bf16(af[m], bfr[n], acc[m][n], 0, 0, 0);

    if (kc < 19) {
      write_k(cur ^ 1);
      __syncthreads();
    }
  }

  int jcol[2];
  float fb2[2], gm[2];
#pragma unroll
  for (int n = 0; n < 2; ++n) {
    jcol[n] = cn * 64 + wn * 32 + n * 16 + col;
    fb2[n] = fcb[jcol[n]];
    gm[n] = gamma[jcol[n]];
  }
#pragma unroll
  for (int m = 0; m < 2; ++m) {
    int rowg = rt * 64 + wm * 32 + m * 16 + g * 4;
#pragma unroll
    for (int j = 0; j < 4; ++j) {
      int row = rowg + j;
#pragma unroll
      for (int n = 0; n < 2; ++n) {
        float xv = (acc[m][n][j] + fb2[n]) * gm[n] + qres[(size_t)row * DM_ + jcol[n]];
        xout[(size_t)row * DM_ + jcol[n]] = f2bf(sane(xv, 1e5f));
      }
    }
  }
}

// -------------------- Kernel C: LayerNorm (x bf16 -> y fp32) --------------------
__global__ __launch_bounds__(256) void ln_kernel(
    const unsigned short* __restrict__ x, const float* __restrict__ lw,
    const float* __restrict__ lb, float* __restrict__ y) {
  const int wid = threadIdx.x >> 6, lane = threadIdx.x & 63;
  const int row = blockIdx.x * 4 + wid;
  const unsigned short* xr = x + (size_t)row * DM_;

  unsigned int u[5];
  float s = 0.f, ss = 0.f;
#pragma unroll
  for (int i = 0; i < 5; ++i) {
    u[i] = *(const unsigned int*)(xr + 2 * (lane + 64 * i));
    float a0 = bf2f((unsigned short)(u[i] & 0xffff));
    float a1 = bf2f((unsigned short)(u[i] >> 16));
    s += a0 + a1;
    ss += a0 * a0 + a1 * a1;
  }
#pragma unroll
  for (int d = 1; d < 64; d <<= 1) {
    s += __shfl_xor(s, d);
    ss += __shfl_xor(ss, d);
  }
  const float mu = s * (1.f / 640.f);
  const float var = ss * (1.f / 640.f) - mu * mu;
  const float rstd = rsqrtf(var + 1e-5f);

  float* yr = y + (size_t)row * DM_;
#pragma unroll
  for (int i = 0; i < 5; ++i) {
    int c0 = 2 * (lane + 64 * i);
    float a0 = bf2f((unsigned short)(u[i] & 0xffff));
    float a1 = bf2f((unsigned short)(u[i] >> 16));
    float2 wv = *(const float2*)(lw + c0);
    float2 bv = *(const float2*)(lb + c0);
    float2 out;
    out.x = (a0 - mu) * rstd * wv.x + bv.x;
    out.y = (a1 - mu) * rstd * wv.y + bv.y;
    *(float2*)(yr + c0) = out;
  }
}

extern "C" void kernel_launch(void* const* d_in, const int* in_sizes, int n_in,
                              void* d_out, int out_size, void* d_ws, size_t ws_size,
                              hipStream_t stream) {
  const float* q = (const float*)d_in[0];
  const float* k = (const float*)d_in[1];
  const float* v = (const float*)d_in[2];
  const float* fw = (const float*)d_in[3];
  const float* fb = (const float*)d_in[4];
  const float* g1 = (const float*)d_in[5];
  const float* lw = (const float*)d_in[6];
  const float* lb = (const float*)d_in[7];

  unsigned short* vtp = (unsigned short*)d_out;                   // 10.62 MB V' tiles
  unsigned char* attn8 = (unsigned char*)d_out + ATTN8_OFF;       // 5.24 MB fp8 attn
  unsigned char* kp8 = (unsigned char*)d_ws;                      // 6.29 MB fp8 Kp
  unsigned short* xws = (unsigned short*)d_ws;                    // x overwrites Kp
  float* y = (float*)d_out;                                        // final overwrite

  prep_kernel<<<dim3(64 * 16), dim3(256), 0, stream>>>(k, v, kp8, vtp);
  attn_kernel<<<dim3(64 * 16), dim3(256), 0, stream>>>(q, kp8, vtp, attn8);
  fc_kernel<<<dim3(128 * 10), dim3(256), 0, stream>>>(attn8, fw, fb, g1, q, xws);
  ln_kernel<<<dim3(8192 / 4), dim3(256), 0, stream>>>(xws, lw, lb, y);
}